// Round 1
// baseline (10638.269 us; speedup 1.0000x reference)
//
#include <hip/hip_runtime.h>
#include <cmath>

#define B_ 1024
#define T_ 75
#define IN_ 768
#define H_ 512
#define G_ 2048

#define EPSF 1e-15f
#define MAXN 0.99999f

// ---------------- helpers ----------------

__device__ inline float sigmoidf_(float x) { return 1.0f / (1.0f + expf(-x)); }

// logmap0 o proj o expmap0 composite scale: s(n) such that out = s * x, n = ||x||
__device__ inline float tangentize_scale(float n) {
    float n1 = fmaxf(n, EPSF);
    float m = fminf(tanhf(n1), MAXN);
    // (logmap0's inner max(.,EPS) is absorbed: tanh(n1) >= 1e-15 always here)
    return atanhf(m) / n1;
}

// proj o expmap0 composite scale (used for time_feats)
__device__ inline float expproj_scale(float n) {
    float n1 = fmaxf(n, EPSF);
    return fminf(tanhf(n1), MAXN) / n1;
}

// block-wide sum reduction, result broadcast to all threads. All threads must call.
__device__ inline float blockReduceSum(float v) {
    __shared__ float sm[8];
    __syncthreads();  // protect smem reuse across consecutive calls
    #pragma unroll
    for (int off = 32; off > 0; off >>= 1) v += __shfl_down(v, off, 64);
    int w = threadIdx.x >> 6, lane = threadIdx.x & 63;
    if (lane == 0) sm[w] = v;
    __syncthreads();
    int nw = (blockDim.x + 63) >> 6;
    if (threadIdx.x == 0) {
        float r = sm[0];
        for (int i = 1; i < nw; ++i) r += sm[i];
        sm[0] = r;
    }
    __syncthreads();
    return sm[0];
}

// ---------------- precompute kernels ----------------

// per (b,t) row of sentence_feats (768): xscale = tangentize_scale(||row||)
__global__ void xscale_kernel(const float* __restrict__ x, float* __restrict__ xscale) {
    int row = blockIdx.x;  // 0 .. B*T-1
    const float* p = x + (size_t)row * IN_;
    float s = 0.f;
    for (int k = threadIdx.x; k < IN_; k += 256) { float v = p[k]; s += v * v; }
    float tot = blockReduceSum(s);
    if (threadIdx.x == 0) xscale[row] = tangentize_scale(sqrtf(tot));
}

// per b row of time_feats (75): tf = proj(expmap0(time_feats)) along T axis
__global__ void tf_kernel(const float* __restrict__ x, float* __restrict__ tf) {
    int b = blockIdx.x;
    float v = (threadIdx.x < T_) ? x[(size_t)b * T_ + threadIdx.x] : 0.f;
    float tot = blockReduceSum(v * v);
    float s = expproj_scale(sqrtf(tot));
    if (threadIdx.x < T_) tf[(size_t)b * T_ + threadIdx.x] = s * v;
}

// ---------------- GEMM: C = act(A1*W1^T + A2*W2^T + bias1 + bias2) ----------------
// A row-major (M x K, ld = lda), W row-major (N x K, ld = K). 64x64 tile, 256 thr, 4x4/thr.
#define BM 64
#define BN 64
#define BK 16

__global__ __launch_bounds__(256) void gemm_nt(
    const float* __restrict__ A1, int lda1, const float* __restrict__ W1, int K1,
    const float* __restrict__ A2, int lda2, const float* __restrict__ W2, int K2,
    const float* __restrict__ rowscale2, int rs_stride, int rs_off,
    const float* __restrict__ bias1, const float* __restrict__ bias2,
    float* __restrict__ C, int ldc, int act)
{
    __shared__ float As[BK][BM + 4];
    __shared__ float Ws[BK][BN + 4];
    const int bm = blockIdx.x * BM, bn = blockIdx.y * BN;
    const int tid = threadIdx.x;
    const int tm = (tid & 15) * 4;
    const int tn = (tid >> 4) * 4;
    const int lm = tid >> 2;          // 0..63
    const int lk = (tid & 3) * 4;     // 0,4,8,12

    float acc[4][4] = {};

    #pragma unroll
    for (int seg = 0; seg < 2; ++seg) {
        const float* A = seg ? A2 : A1;
        const float* W = seg ? W2 : W1;
        const int K   = seg ? K2 : K1;
        const int lda = seg ? lda2 : lda1;
        if (W == nullptr || K == 0) continue;
        float rs = 1.0f;
        if (seg == 1 && rowscale2) rs = rowscale2[(size_t)(bm + lm) * rs_stride + rs_off];

        for (int k0 = 0; k0 < K; k0 += BK) {
            float4 a = *reinterpret_cast<const float4*>(A + (size_t)(bm + lm) * lda + k0 + lk);
            if (seg == 1 && rowscale2) { a.x *= rs; a.y *= rs; a.z *= rs; a.w *= rs; }
            As[lk + 0][lm] = a.x; As[lk + 1][lm] = a.y; As[lk + 2][lm] = a.z; As[lk + 3][lm] = a.w;
            float4 w = *reinterpret_cast<const float4*>(W + (size_t)(bn + lm) * K + k0 + lk);
            Ws[lk + 0][lm] = w.x; Ws[lk + 1][lm] = w.y; Ws[lk + 2][lm] = w.z; Ws[lk + 3][lm] = w.w;
            __syncthreads();
            #pragma unroll
            for (int kk = 0; kk < BK; ++kk) {
                const float4 av = *reinterpret_cast<const float4*>(&As[kk][tm]);
                const float4 wv = *reinterpret_cast<const float4*>(&Ws[kk][tn]);
                float aa[4] = {av.x, av.y, av.z, av.w};
                float ww[4] = {wv.x, wv.y, wv.z, wv.w};
                #pragma unroll
                for (int i = 0; i < 4; ++i)
                    #pragma unroll
                    for (int j = 0; j < 4; ++j)
                        acc[i][j] = fmaf(aa[i], ww[j], acc[i][j]);
            }
            __syncthreads();
        }
    }

    float bb[4];
    #pragma unroll
    for (int j = 0; j < 4; ++j) {
        int col = bn + tn + j;
        bb[j] = (bias1 ? bias1[col] : 0.f) + (bias2 ? bias2[col] : 0.f);
    }
    #pragma unroll
    for (int i = 0; i < 4; ++i) {
        float4 o;
        float vals[4];
        #pragma unroll
        for (int j = 0; j < 4; ++j) {
            float v = acc[i][j] + bb[j];
            if (act == 1) v = sigmoidf_(v);
            else if (act == 2) v = tanhf(v);
            else if (act == 3) v = fmaxf(v, 0.f);
            vals[j] = v;
        }
        o.x = vals[0]; o.y = vals[1]; o.z = vals[2]; o.w = vals[3];
        *reinterpret_cast<float4*>(C + (size_t)(bm + tm + i) * ldc + bn + tn) = o;
    }
}

// ---------------- encoder pointwise + renormalize ----------------
// gates already sigmoid'd, cs1 already tanh'd. States stored in tangent space.
__global__ __launch_bounds__(512) void enc_pointwise(
    const float* __restrict__ gates, const float* __restrict__ cs1,
    const float* __restrict__ tf, int t,
    float* __restrict__ ht, float* __restrict__ ct)
{
    int b = blockIdx.x, j = threadIdx.x;
    const float* g = gates + (size_t)b * G_;
    float f    = g[j];
    float i_   = g[H_ + j];
    float o    = g[2 * H_ + j];
    float ctmp = g[3 * H_ + j];
    float c1   = cs1[(size_t)b * H_ + j];
    float ctv  = ct[(size_t)b * H_ + j];
    float ts   = tf[(size_t)b * T_ + t];

    float c_adj = ctv - c1 + c1 * ts;
    float c_new = f * c_adj + i_ * ctmp;
    float h_new = o * tanhf(c_new);

    float nc = blockReduceSum(c_new * c_new);
    float nh = blockReduceSum(h_new * h_new);
    float sc = tangentize_scale(sqrtf(nc));
    float sh = tangentize_scale(sqrtf(nh));
    ct[(size_t)b * H_ + j] = sc * c_new;
    ht[(size_t)b * H_ + j] = sh * h_new;
}

// proj() applied to tangent rows of ht and ct in place (hx, cx)
__global__ __launch_bounds__(512) void proj_rows(float* __restrict__ ht, float* __restrict__ ct) {
    int b = blockIdx.x;  // 0..2B-1
    float* p = (b < B_) ? (ht + (size_t)b * H_) : (ct + (size_t)(b - B_) * H_);
    float v = p[threadIdx.x];
    float n = sqrtf(blockReduceSum(v * v));
    n = fmaxf(n, EPSF);
    if (n > MAXN) p[threadIdx.x] = v / n * MAXN;
}

// num_spans = softmax(hx @ W_span^T + b_span), N=4
__global__ __launch_bounds__(256) void span_kernel(
    const float* __restrict__ hx, const float* __restrict__ W, const float* __restrict__ bias,
    float* __restrict__ out)
{
    int b = blockIdx.x;
    int w = threadIdx.x >> 6, lane = threadIdx.x & 63;
    const float* h = hx + (size_t)b * H_;
    float s = 0.f;
    for (int k = lane; k < H_; k += 64) s += h[k] * W[(size_t)w * H_ + k];
    #pragma unroll
    for (int off = 32; off > 0; off >>= 1) s += __shfl_down(s, off, 64);
    __shared__ float lg[4];
    if (lane == 0) lg[w] = s + bias[w];
    __syncthreads();
    if (threadIdx.x < 4) {
        float m = fmaxf(fmaxf(lg[0], lg[1]), fmaxf(lg[2], lg[3]));
        float den = expf(lg[0] - m) + expf(lg[1] - m) + expf(lg[2] - m) + expf(lg[3] - m);
        out[(size_t)b * 4 + threadIdx.x] = expf(lg[threadIdx.x] - m) / den;
    }
}

// decoder pointwise LSTM cell (torch gate order i,f,g,o), gates are raw pre-activations
__global__ __launch_bounds__(256) void dec_pointwise(
    const float* __restrict__ gates, float* __restrict__ h, float* __restrict__ c)
{
    int idx = blockIdx.x * blockDim.x + threadIdx.x;  // B*H
    int b = idx >> 9, j = idx & (H_ - 1);
    const float* g = gates + (size_t)b * G_;
    float i_ = g[j];
    float f_ = g[H_ + j];
    float g_ = g[2 * H_ + j];
    float o_ = g[3 * H_ + j];
    float cv = sigmoidf_(f_) * c[idx] + sigmoidf_(i_) * tanhf(g_);
    float hv = sigmoidf_(o_) * tanhf(cv);
    c[idx] = cv;
    h[idx] = hv;
}

// out = softmax(h @ W_fc_out^T + b_fc_out), N=2 -> d_out[4096 + b*20 + step*2 + {0,1}]
__global__ __launch_bounds__(128) void out2_kernel(
    const float* __restrict__ h, const float* __restrict__ W, const float* __restrict__ bias,
    float* __restrict__ out, int step)
{
    int b = blockIdx.x;
    int w = threadIdx.x >> 6, lane = threadIdx.x & 63;
    const float* hb = h + (size_t)b * H_;
    float s = 0.f;
    for (int k = lane; k < H_; k += 64) s += hb[k] * W[(size_t)w * H_ + k];
    #pragma unroll
    for (int off = 32; off > 0; off >>= 1) s += __shfl_down(s, off, 64);
    __shared__ float lg[2];
    if (lane == 0) lg[w] = s + bias[w];
    __syncthreads();
    if (threadIdx.x < 2) {
        float m = fmaxf(lg[0], lg[1]);
        float den = expf(lg[0] - m) + expf(lg[1] - m);
        out[4096 + (size_t)b * 20 + step * 2 + threadIdx.x] = expf(lg[threadIdx.x] - m) / den;
    }
}

// ---------------- launch ----------------

extern "C" void kernel_launch(void* const* d_in, const int* in_sizes, int n_in,
                              void* d_out, int out_size, void* d_ws, size_t ws_size,
                              hipStream_t stream) {
    (void)in_sizes; (void)n_in; (void)out_size; (void)ws_size;
    const float* sent    = (const float*)d_in[0];
    const float* timef   = (const float*)d_in[1];
    const float* Wd      = (const float*)d_in[2];
    const float* bd      = (const float*)d_in[3];
    const float* W_all   = (const float*)d_in[4];
    const float* b_all   = (const float*)d_in[5];
    const float* U_all   = (const float*)d_in[6];
    const float* b_U     = (const float*)d_in[7];
    const float* W_ih    = (const float*)d_in[8];
    const float* b_ih    = (const float*)d_in[9];
    const float* W_hh    = (const float*)d_in[10];
    const float* b_hh    = (const float*)d_in[11];
    const float* W_fc_in = (const float*)d_in[12];
    const float* b_fc_in = (const float*)d_in[13];
    const float* W_fc_out= (const float*)d_in[14];
    const float* b_fc_out= (const float*)d_in[15];
    const float* W_span  = (const float*)d_in[16];
    const float* b_span  = (const float*)d_in[17];
    float* out = (float*)d_out;

    float* ws = (float*)d_ws;
    size_t off = 0;
    auto alloc = [&](size_t n) { float* p = ws + off; off += (n + 63) & ~(size_t)63; return p; };
    float* xscale = alloc((size_t)B_ * T_);
    float* tf     = alloc((size_t)B_ * T_);
    float* ht     = alloc((size_t)B_ * H_);
    float* ct     = alloc((size_t)B_ * H_);
    float* gates  = alloc((size_t)B_ * G_);
    float* cs1    = alloc((size_t)B_ * H_);
    float* inp    = alloc((size_t)B_ * IN_);

    hipMemsetAsync(ht, 0, (size_t)B_ * H_ * sizeof(float), stream);
    hipMemsetAsync(ct, 0, (size_t)B_ * H_ * sizeof(float), stream);
    hipMemsetAsync(inp, 0, (size_t)B_ * IN_ * sizeof(float), stream);

    xscale_kernel<<<B_ * T_, 256, 0, stream>>>(sent, xscale);
    tf_kernel<<<B_, 128, 0, stream>>>(timef, tf);

    // encoder: 75 steps
    for (int t = 0; t < T_; ++t) {
        // gates = sigmoid(ht@W_all^T + b_all + xt@U_all^T + b_U); xt = xscale[b,t]*sent[b,t,:]
        gemm_nt<<<dim3(B_ / BM, G_ / BN), 256, 0, stream>>>(
            ht, H_, W_all, H_,
            sent + (size_t)t * IN_, T_ * IN_, U_all, IN_,
            xscale, T_, t,
            b_all, b_U, gates, G_, 1);
        // cs1 = tanh(ct@Wd^T + bd)
        gemm_nt<<<dim3(B_ / BM, H_ / BN), 256, 0, stream>>>(
            ct, H_, Wd, H_,
            nullptr, 0, nullptr, 0,
            nullptr, 0, 0,
            bd, nullptr, cs1, H_, 2);
        enc_pointwise<<<B_, H_, 0, stream>>>(gates, cs1, tf, t, ht, ct);
    }

    // hx = proj(ht), cx = proj(ct) in place
    proj_rows<<<2 * B_, H_, 0, stream>>>(ht, ct);
    span_kernel<<<B_, 256, 0, stream>>>(ht, W_span, b_span, out);

    // decoder: 10 steps (h=ht buffer, c=ct buffer)
    for (int s = 0; s < 10; ++s) {
        gemm_nt<<<dim3(B_ / BM, G_ / BN), 256, 0, stream>>>(
            inp, IN_, W_ih, IN_,
            ht, H_, W_hh, H_,
            nullptr, 0, 0,
            b_ih, b_hh, gates, G_, 0);
        dec_pointwise<<<(B_ * H_) / 256, 256, 0, stream>>>(gates, ht, ct);
        gemm_nt<<<dim3(B_ / BM, IN_ / BN), 256, 0, stream>>>(
            ht, H_, W_fc_in, H_,
            nullptr, 0, nullptr, 0,
            nullptr, 0, 0,
            b_fc_in, nullptr, inp, IN_, 3);
        out2_kernel<<<B_, 128, 0, stream>>>(ht, W_fc_out, b_fc_out, out, s);
    }
}

// Round 2
// 3701.264 us; speedup vs baseline: 2.8742x; 2.8742x over previous
//
#include <hip/hip_runtime.h>
#include <cmath>

#define B_ 1024
#define T_ 75
#define IN_ 768
#define H_ 512
#define G_ 2048

#define EPSF 1e-15f
#define MAXN 0.99999f

typedef __bf16 bf16_t;
typedef bf16_t bf16x8 __attribute__((ext_vector_type(8)));
typedef float f32x4 __attribute__((ext_vector_type(4)));
typedef unsigned short u16;
typedef u16 u16x8 __attribute__((ext_vector_type(8)));

// ---------------- scalar helpers ----------------

__device__ inline float sigmoidf_(float x) { return 1.0f / (1.0f + expf(-x)); }

__device__ inline u16 f2bf(float f) {  // RNE float->bf16 (finite inputs)
    unsigned u = __builtin_bit_cast(unsigned, f);
    u = u + 0x7FFFu + ((u >> 16) & 1u);
    return (u16)(u >> 16);
}
__device__ inline float bf2f(u16 h) {
    return __builtin_bit_cast(float, (unsigned)h << 16);
}

// logmap0 o proj o expmap0 composite scale
__device__ inline float tangentize_scale(float n) {
    float n1 = fmaxf(n, EPSF);
    float m = fminf(tanhf(n1), MAXN);
    return atanhf(m) / n1;
}
// proj o expmap0 composite scale (time feats)
__device__ inline float expproj_scale(float n) {
    float n1 = fmaxf(n, EPSF);
    return fminf(tanhf(n1), MAXN) / n1;
}

__device__ inline float blockReduceSum(float v) {
    __shared__ float sm[8];
    __syncthreads();
    #pragma unroll
    for (int off = 32; off > 0; off >>= 1) v += __shfl_down(v, off, 64);
    int w = threadIdx.x >> 6, lane = threadIdx.x & 63;
    if (lane == 0) sm[w] = v;
    __syncthreads();
    int nw = (blockDim.x + 63) >> 6;
    if (threadIdx.x == 0) {
        float r = sm[0];
        for (int i = 1; i < nw; ++i) r += sm[i];
        sm[0] = r;
    }
    __syncthreads();
    return sm[0];
}

// ---------------- small precompute kernels ----------------

__global__ void cvt_f32_bf16(const float* __restrict__ s, u16* __restrict__ d, int n) {
    int i = (blockIdx.x * 256 + threadIdx.x) * 4;
    if (i < n) {
        float4 f = *reinterpret_cast<const float4*>(s + i);
        d[i + 0] = f2bf(f.x); d[i + 1] = f2bf(f.y);
        d[i + 2] = f2bf(f.z); d[i + 3] = f2bf(f.w);
    }
}

// per (b,t) row of sentence_feats: xscale = tangentize_scale(||row||)
__global__ void xscale_kernel(const float* __restrict__ x, float* __restrict__ xscale) {
    int row = blockIdx.x;
    const float* p = x + (size_t)row * IN_;
    float s = 0.f;
    for (int k = threadIdx.x; k < IN_; k += 256) { float v = p[k]; s += v * v; }
    float tot = blockReduceSum(s);
    if (threadIdx.x == 0) xscale[row] = tangentize_scale(sqrtf(tot));
}

// tf = proj(expmap0(time_feats)) rowwise over T
__global__ void tf_kernel(const float* __restrict__ x, float* __restrict__ tf) {
    int b = blockIdx.x;
    float v = (threadIdx.x < T_) ? x[(size_t)b * T_ + threadIdx.x] : 0.f;
    float tot = blockReduceSum(v * v);
    float s = expproj_scale(sqrtf(tot));
    if (threadIdx.x < T_) tf[(size_t)b * T_ + threadIdx.x] = s * v;
}

// ---------------- MFMA GEMM ----------------
// C = act( sum_seg A_s * W_s^T + bias1 + bias2 + addend )
// A: row-major (bf16 mirrors, or fp32 with per-row scale), W: bf16 row-major N x K.
// Tile TM x TN, 256 threads = 4 waves in 2x2 grid, BK=64, XOR-swizzled LDS.

struct Seg {
    const void* A; int lda; int fp32;
    const float* rs; int rs_stride; int rs_off;
    const u16* W; int K;
};
struct Job {
    Seg s[2];
    const float* bias1; const float* bias2;
    const u16* add; long ld_add;
    void* C; int ldc; int act; int out_bf16;
    int nb;
};

template<int TM, int TN>
__global__ __launch_bounds__(256) void mfma_gemm(Job j0, Job j1, int nb0, int xcd) {
    static_assert(TM % 32 == 0 && TN % 32 == 0, "");
    constexpr int FM = TM / 32;
    constexpr int FN = TN / 32;
    __shared__ __align__(16) unsigned char As[TM * 128];
    __shared__ __align__(16) unsigned char Ws[TN * 128];

    int bid = (int)blockIdx.x;
    if (xcd) { int total = (int)gridDim.x; bid = (bid & 7) * (total >> 3) + (bid >> 3); }
    const Job& J = (bid < nb0) ? j0 : j1;
    int local = bid - (bid < nb0 ? 0 : nb0);
    const int bn = (local % J.nb) * TN;
    const int bm = (local / J.nb) * TM;

    const int tid = threadIdx.x;
    const int lane = tid & 63;
    const int wid = tid >> 6;
    const int wr = wid >> 1, wc = wid & 1;
    const int l15 = lane & 15, l4 = lane >> 4;

    f32x4 acc[FM][FN] = {};

    #pragma unroll
    for (int seg = 0; seg < 2; ++seg) {
        const Seg& S = J.s[seg];
        if (!S.W) continue;
        for (int k0 = 0; k0 < S.K; k0 += 64) {
            __syncthreads();
            // ---- stage A tile (TM x 64 bf16), swizzled 16B chunks ----
            constexpr int CA = TM * 8 / 256;
            #pragma unroll
            for (int c = 0; c < CA; ++c) {
                int ch = c * 256 + tid;
                int r = ch >> 3, q = ch & 7;
                unsigned off = (unsigned)(r * 128 + ((q ^ (r & 7)) * 16));
                if (S.fp32) {
                    const float* src = (const float*)S.A + (size_t)(bm + r) * S.lda + k0 + q * 8;
                    float rs = S.rs ? S.rs[(size_t)(bm + r) * S.rs_stride + S.rs_off] : 1.f;
                    float4 f0 = *reinterpret_cast<const float4*>(src);
                    float4 f1 = *reinterpret_cast<const float4*>(src + 4);
                    u16x8 v;
                    v[0] = f2bf(f0.x * rs); v[1] = f2bf(f0.y * rs);
                    v[2] = f2bf(f0.z * rs); v[3] = f2bf(f0.w * rs);
                    v[4] = f2bf(f1.x * rs); v[5] = f2bf(f1.y * rs);
                    v[6] = f2bf(f1.z * rs); v[7] = f2bf(f1.w * rs);
                    *reinterpret_cast<u16x8*>(As + off) = v;
                } else {
                    const u16* src = (const u16*)S.A + (size_t)(bm + r) * S.lda + k0 + q * 8;
                    *reinterpret_cast<u16x8*>(As + off) = *reinterpret_cast<const u16x8*>(src);
                }
            }
            // ---- stage W tile (TN x 64 bf16) ----
            constexpr int CW = TN * 8 / 256;
            #pragma unroll
            for (int c = 0; c < CW; ++c) {
                int ch = c * 256 + tid;
                int r = ch >> 3, q = ch & 7;
                unsigned off = (unsigned)(r * 128 + ((q ^ (r & 7)) * 16));
                const u16* src = S.W + (size_t)(bn + r) * S.K + k0 + q * 8;
                *reinterpret_cast<u16x8*>(Ws + off) = *reinterpret_cast<const u16x8*>(src);
            }
            __syncthreads();
            // ---- compute: 2 k-substeps of 32 ----
            #pragma unroll
            for (int ks = 0; ks < 2; ++ks) {
                bf16x8 af[FM], bfr[FN];
                #pragma unroll
                for (int m = 0; m < FM; ++m) {
                    int r = wr * (TM / 2) + m * 16 + l15;
                    af[m] = *reinterpret_cast<const bf16x8*>(
                        As + r * 128 + (((ks * 4 + l4) ^ (r & 7)) * 16));
                }
                #pragma unroll
                for (int n = 0; n < FN; ++n) {
                    int r = wc * (TN / 2) + n * 16 + l15;
                    bfr[n] = *reinterpret_cast<const bf16x8*>(
                        Ws + r * 128 + (((ks * 4 + l4) ^ (r & 7)) * 16));
                }
                #pragma unroll
                for (int m = 0; m < FM; ++m)
                    #pragma unroll
                    for (int n = 0; n < FN; ++n)
                        acc[m][n] = __builtin_amdgcn_mfma_f32_16x16x32_bf16(
                            af[m], bfr[n], acc[m][n], 0, 0, 0);
            }
        }
    }

    // ---- epilogue ----
    #pragma unroll
    for (int m = 0; m < FM; ++m) {
        #pragma unroll
        for (int n = 0; n < FN; ++n) {
            int col = bn + wc * (TN / 2) + n * 16 + l15;
            float badd = (J.bias1 ? J.bias1[col] : 0.f) + (J.bias2 ? J.bias2[col] : 0.f);
            #pragma unroll
            for (int v = 0; v < 4; ++v) {
                int row = bm + wr * (TM / 2) + m * 16 + l4 * 4 + v;
                float val = acc[m][n][v] + badd;
                if (J.add) val += bf2f(J.add[(size_t)row * J.ld_add + col]);
                if (J.act == 1) val = sigmoidf_(val);
                else if (J.act == 2) val = tanhf(val);
                else if (J.act == 3) val = fmaxf(val, 0.f);
                if (J.out_bf16) ((u16*)J.C)[(size_t)row * J.ldc + col] = f2bf(val);
                else ((float*)J.C)[(size_t)row * J.ldc + col] = val;
            }
        }
    }
}

// ---------------- encoder pointwise (+ bf16 mirrors) ----------------

__global__ __launch_bounds__(512) void enc_pointwise(
    const float* __restrict__ gates, const float* __restrict__ cs1,
    const float* __restrict__ tf, int t,
    float* __restrict__ ht, float* __restrict__ ct,
    u16* __restrict__ htb, u16* __restrict__ ctb)
{
    int b = blockIdx.x, j = threadIdx.x;
    const float* g = gates + (size_t)b * G_;
    float f    = g[j];
    float i_   = g[H_ + j];
    float o    = g[2 * H_ + j];
    float ctmp = g[3 * H_ + j];
    float c1   = cs1[(size_t)b * H_ + j];
    float ctv  = ct[(size_t)b * H_ + j];
    float ts   = tf[(size_t)b * T_ + t];

    float c_adj = ctv - c1 + c1 * ts;
    float c_new = f * c_adj + i_ * ctmp;
    float h_new = o * tanhf(c_new);

    float nc = blockReduceSum(c_new * c_new);
    float nh = blockReduceSum(h_new * h_new);
    float sc = tangentize_scale(sqrtf(nc));
    float sh = tangentize_scale(sqrtf(nh));
    float cv = sc * c_new, hv = sh * h_new;
    size_t idx = (size_t)b * H_ + j;
    ct[idx] = cv; ht[idx] = hv;
    ctb[idx] = f2bf(cv); htb[idx] = f2bf(hv);
}

// proj() on tangent rows of ht/ct in place, refresh mirrors
__global__ __launch_bounds__(512) void proj_rows(
    float* __restrict__ ht, float* __restrict__ ct,
    u16* __restrict__ htb, u16* __restrict__ ctb)
{
    int b = blockIdx.x;  // 0..2B-1
    float* p = (b < B_) ? (ht + (size_t)b * H_) : (ct + (size_t)(b - B_) * H_);
    u16*  pb = (b < B_) ? (htb + (size_t)b * H_) : (ctb + (size_t)(b - B_) * H_);
    float v = p[threadIdx.x];
    float n = sqrtf(blockReduceSum(v * v));
    n = fmaxf(n, EPSF);
    if (n > MAXN) v = v / n * MAXN;
    p[threadIdx.x] = v;
    pb[threadIdx.x] = f2bf(v);
}

__global__ __launch_bounds__(256) void span_kernel(
    const float* __restrict__ hx, const float* __restrict__ W, const float* __restrict__ bias,
    float* __restrict__ out)
{
    int b = blockIdx.x;
    int w = threadIdx.x >> 6, lane = threadIdx.x & 63;
    const float* h = hx + (size_t)b * H_;
    float s = 0.f;
    for (int k = lane; k < H_; k += 64) s += h[k] * W[(size_t)w * H_ + k];
    #pragma unroll
    for (int off = 32; off > 0; off >>= 1) s += __shfl_down(s, off, 64);
    __shared__ float lg[4];
    if (lane == 0) lg[w] = s + bias[w];
    __syncthreads();
    if (threadIdx.x < 4) {
        float m = fmaxf(fmaxf(lg[0], lg[1]), fmaxf(lg[2], lg[3]));
        float den = expf(lg[0] - m) + expf(lg[1] - m) + expf(lg[2] - m) + expf(lg[3] - m);
        out[(size_t)b * 4 + threadIdx.x] = expf(lg[threadIdx.x] - m) / den;
    }
}

__global__ __launch_bounds__(256) void dec_pointwise(
    const float* __restrict__ gates, float* __restrict__ h, float* __restrict__ c,
    u16* __restrict__ hb)
{
    int idx = blockIdx.x * blockDim.x + threadIdx.x;  // B*H
    int b = idx >> 9, j = idx & (H_ - 1);
    const float* g = gates + (size_t)b * G_;
    float i_ = g[j];
    float f_ = g[H_ + j];
    float g_ = g[2 * H_ + j];
    float o_ = g[3 * H_ + j];
    float cv = sigmoidf_(f_) * c[idx] + sigmoidf_(i_) * tanhf(g_);
    float hv = sigmoidf_(o_) * tanhf(cv);
    c[idx] = cv;
    h[idx] = hv;
    hb[idx] = f2bf(hv);
}

__global__ __launch_bounds__(128) void out2_kernel(
    const float* __restrict__ h, const float* __restrict__ W, const float* __restrict__ bias,
    float* __restrict__ out, int step)
{
    int b = blockIdx.x;
    int w = threadIdx.x >> 6, lane = threadIdx.x & 63;
    const float* hb = h + (size_t)b * H_;
    float s = 0.f;
    for (int k = lane; k < H_; k += 64) s += hb[k] * W[(size_t)w * H_ + k];
    #pragma unroll
    for (int off = 32; off > 0; off >>= 1) s += __shfl_down(s, off, 64);
    __shared__ float lg[2];
    if (lane == 0) lg[w] = s + bias[w];
    __syncthreads();
    if (threadIdx.x < 2) {
        float m = fmaxf(lg[0], lg[1]);
        float den = expf(lg[0] - m) + expf(lg[1] - m);
        out[4096 + (size_t)b * 20 + step * 2 + threadIdx.x] = expf(lg[threadIdx.x] - m) / den;
    }
}

// ---------------- launch ----------------

extern "C" void kernel_launch(void* const* d_in, const int* in_sizes, int n_in,
                              void* d_out, int out_size, void* d_ws, size_t ws_size,
                              hipStream_t stream) {
    (void)in_sizes; (void)n_in; (void)out_size;
    const float* sent    = (const float*)d_in[0];
    const float* timef   = (const float*)d_in[1];
    const float* Wd      = (const float*)d_in[2];
    const float* bd      = (const float*)d_in[3];
    const float* W_all   = (const float*)d_in[4];
    const float* b_all   = (const float*)d_in[5];
    const float* U_all   = (const float*)d_in[6];
    const float* b_U     = (const float*)d_in[7];
    const float* W_ih    = (const float*)d_in[8];
    const float* b_ih    = (const float*)d_in[9];
    const float* W_hh    = (const float*)d_in[10];
    const float* b_hh    = (const float*)d_in[11];
    const float* W_fc_in = (const float*)d_in[12];
    const float* b_fc_in = (const float*)d_in[13];
    const float* W_fc_out= (const float*)d_in[14];
    const float* b_fc_out= (const float*)d_in[15];
    const float* W_span  = (const float*)d_in[16];
    const float* b_span  = (const float*)d_in[17];
    float* out = (float*)d_out;

    char* ws = (char*)d_ws;
    size_t off = 0;
    auto alloc = [&](size_t bytes) -> void* {
        void* p = ws + off; off = (off + bytes + 255) & ~(size_t)255; return p;
    };
    float* xscale = (float*)alloc((size_t)B_ * T_ * 4);
    float* tf     = (float*)alloc((size_t)B_ * T_ * 4);
    float* ht     = (float*)alloc((size_t)B_ * H_ * 4);
    float* ct     = (float*)alloc((size_t)B_ * H_ * 4);
    float* gates  = (float*)alloc((size_t)B_ * G_ * 4);
    float* cs1    = (float*)alloc((size_t)B_ * H_ * 4);
    u16* htb      = (u16*)alloc((size_t)B_ * H_ * 2);
    u16* ctb      = (u16*)alloc((size_t)B_ * H_ * 2);
    u16* inpb     = (u16*)alloc((size_t)B_ * IN_ * 2);
    u16* Wall_b   = (u16*)alloc((size_t)G_ * H_ * 2);
    u16* Uall_b   = (u16*)alloc((size_t)G_ * IN_ * 2);
    u16* Wd_b     = (u16*)alloc((size_t)H_ * H_ * 2);
    u16* Wih_b    = (u16*)alloc((size_t)G_ * IN_ * 2);
    u16* Whh_b    = (u16*)alloc((size_t)G_ * H_ * 2);
    u16* Wfcin_b  = (u16*)alloc((size_t)IN_ * H_ * 2);
    size_t xu_bytes = (size_t)B_ * T_ * G_ * 2;
    bool pathA = (off + xu_bytes + 256) <= ws_size;
    u16* XU = pathA ? (u16*)alloc(xu_bytes) : nullptr;

    hipMemsetAsync(ht, 0, (size_t)B_ * H_ * 4, stream);
    hipMemsetAsync(ct, 0, (size_t)B_ * H_ * 4, stream);
    hipMemsetAsync(htb, 0, (size_t)B_ * H_ * 2, stream);
    hipMemsetAsync(ctb, 0, (size_t)B_ * H_ * 2, stream);
    hipMemsetAsync(inpb, 0, (size_t)B_ * IN_ * 2, stream);

    auto cvt = [&](const float* s, u16* d, int n) {
        cvt_f32_bf16<<<(n / 4 + 255) / 256, 256, 0, stream>>>(s, d, n);
    };
    cvt(W_all, Wall_b, G_ * H_);
    cvt(U_all, Uall_b, G_ * IN_);
    cvt(Wd, Wd_b, H_ * H_);
    cvt(W_ih, Wih_b, G_ * IN_);
    cvt(W_hh, Whh_b, G_ * H_);
    cvt(W_fc_in, Wfcin_b, IN_ * H_);

    xscale_kernel<<<B_ * T_, 256, 0, stream>>>(sent, xscale);
    tf_kernel<<<B_, 128, 0, stream>>>(timef, tf);

    Job jz = {};  // zero job template

    if (pathA) {
        // XU[b*T+t][:] = xt @ U_all^T + b_U + b_all   (bf16)
        Job j = jz;
        j.s[0] = Seg{sent, IN_, 1, xscale, 1, 0, Uall_b, IN_};
        j.bias1 = b_U; j.bias2 = b_all;
        j.C = XU; j.ldc = G_; j.act = 0; j.out_bf16 = 1;
        j.nb = G_ / 128;
        int grid = (B_ * T_ / 128) * j.nb;  // 600*16 = 9600
        mfma_gemm<128, 128><<<grid, 256, 0, stream>>>(j, j, grid, 1);
    }

    // ---- encoder ----
    for (int t = 0; t < T_; ++t) {
        Job jg = jz;  // gates = sigmoid(htb@W_all^T [+ xt@U_all^T] + biases/XU)
        jg.s[0] = Seg{htb, H_, 0, nullptr, 0, 0, Wall_b, H_};
        if (pathA) {
            jg.add = XU + (size_t)t * G_; jg.ld_add = (long)T_ * G_;
        } else {
            jg.s[1] = Seg{sent + (size_t)t * IN_, T_ * IN_, 1, xscale, T_, t, Uall_b, IN_};
            jg.bias1 = b_all; jg.bias2 = b_U;
        }
        jg.C = gates; jg.ldc = G_; jg.act = 1; jg.nb = G_ / 64;  // 32

        Job jc = jz;  // cs1 = tanh(ctb@Wd^T + bd)
        jc.s[0] = Seg{ctb, H_, 0, nullptr, 0, 0, Wd_b, H_};
        jc.bias1 = bd;
        jc.C = cs1; jc.ldc = H_; jc.act = 2; jc.nb = H_ / 64;  // 8

        int nb0 = (B_ / 64) * jg.nb;            // 512
        int grid = nb0 + (B_ / 64) * jc.nb;     // 640
        mfma_gemm<64, 64><<<grid, 256, 0, stream>>>(jg, jc, nb0, 0);
        enc_pointwise<<<B_, H_, 0, stream>>>(gates, cs1, tf, t, ht, ct, htb, ctb);
    }

    proj_rows<<<2 * B_, H_, 0, stream>>>(ht, ct, htb, ctb);
    span_kernel<<<B_, 256, 0, stream>>>(ht, W_span, b_span, out);

    // ---- decoder ----
    for (int s = 0; s < 10; ++s) {
        Job jg = jz;  // raw gates = inp@W_ih^T + b_ih + h@W_hh^T + b_hh
        jg.s[0] = Seg{inpb, IN_, 0, nullptr, 0, 0, Wih_b, IN_};
        jg.s[1] = Seg{htb, H_, 0, nullptr, 0, 0, Whh_b, H_};
        jg.bias1 = b_ih; jg.bias2 = b_hh;
        jg.C = gates; jg.ldc = G_; jg.act = 0; jg.nb = G_ / 64;
        int grid = (B_ / 64) * jg.nb;  // 512
        mfma_gemm<64, 64><<<grid, 256, 0, stream>>>(jg, jg, grid, 0);

        dec_pointwise<<<(B_ * H_) / 256, 256, 0, stream>>>(gates, ht, ct, htb);

        Job jf = jz;  // inp = relu(h@W_fc_in^T + b_fc_in), bf16 out
        jf.s[0] = Seg{htb, H_, 0, nullptr, 0, 0, Wfcin_b, H_};
        jf.bias1 = b_fc_in;
        jf.C = inpb; jf.ldc = IN_; jf.act = 3; jf.out_bf16 = 1; jf.nb = IN_ / 64;  // 12
        int gridf = (B_ / 64) * jf.nb;  // 192
        mfma_gemm<64, 64><<<gridf, 256, 0, stream>>>(jf, jf, gridf, 0);

        out2_kernel<<<B_, 128, 0, stream>>>(ht, W_fc_out, b_fc_out, out, s);
    }
}